// Round 14
// baseline (1818.990 us; speedup 1.0000x reference)
//
#include <hip/hip_runtime.h>
#include <hip/hip_bf16.h>

// ESN: h_m = tanh(W_res h_{m-1} + W_in x_{m-1} + b_in), readout on all states.
// Recurrence: 4 independent batch-clusters of 64 WGs (full W_res copy per
// cluster in aggregate LDS as i8 digit planes). h as packed i16 digit pairs
// in a FRESH SLOT PER STEP (no ring): producers store sc0sc1 (-> memory-side
// L3), consumers use PLAIN CACHED loads after the flag gate -> per-XCD L2
// dedups the broadcast (~8x less L3 traffic, L2-hit latency). Per-wave
// producer flags; one syncthreads/step; distributed epilogue.
// mfma_i32_16x16x64_i8, all 4 digit products -> exact integer GEMM.

#define B_   64
#define T_   256
#define DIN  512
#define DRES 2048
#define DOUT 512
#define SLP  131072   // elements per packed-h slot (B*DRES)
#define SLQB 262144   // bytes per packed-h slot

typedef __attribute__((ext_vector_type(8))) short short8;
typedef __attribute__((ext_vector_type(4))) float f32x4;
typedef __attribute__((ext_vector_type(4))) int i32x4;

__device__ __forceinline__ unsigned short f2bf(float x) {
    unsigned int u = __float_as_uint(x);
    unsigned int r = u + 0x7fffu + ((u >> 16) & 1u);
    return (unsigned short)(r >> 16);
}
__device__ __forceinline__ float bf2f(unsigned short h) {
    return __uint_as_float(((unsigned int)h) << 16);
}

// ---------------- split f32 -> bf16 hi/lo ----------------
__global__ void split4_kern(const float4* __restrict__ src,
                            ushort4* __restrict__ hi, ushort4* __restrict__ lo, int n4) {
    int i = blockIdx.x * blockDim.x + threadIdx.x;
    int st = gridDim.x * blockDim.x;
    for (; i < n4; i += st) {
        float4 v = src[i];
        ushort4 h, l;
        h.x = f2bf(v.x); l.x = f2bf(v.x - bf2f(h.x));
        h.y = f2bf(v.y); l.y = f2bf(v.y - bf2f(h.y));
        h.z = f2bf(v.z); l.z = f2bf(v.z - bf2f(h.z));
        h.w = f2bf(v.w); l.w = f2bf(v.w - bf2f(h.w));
        hi[i] = h; lo[i] = l;
    }
}

// ---------------- quantize f32 -> two signed-i8 digit planes (for W) ----------------
__global__ void quant_kern(const float* __restrict__ src, float scale,
                           char* __restrict__ d1, char* __restrict__ d0, int n) {
    int i = blockIdx.x * blockDim.x + threadIdx.x;
    int st = gridDim.x * blockDim.x;
    for (; i < n; i += st) {
        int q = (int)rintf(src[i] * scale);
        q = min(max(q, -32640), 32639);
        int h1 = (q + 128) >> 8;
        d1[i] = (char)h1;
        d0[i] = (char)(q - (h1 << 8));
    }
}

// ---------------- quantize f32 -> packed i16 digit pair (for h_0) ----------------
__global__ void quantp_kern(const float* __restrict__ src, float scale,
                            unsigned short* __restrict__ dst, int n) {
    int i = blockIdx.x * blockDim.x + threadIdx.x;
    int st = gridDim.x * blockDim.x;
    for (; i < n; i += st) {
        int q = (int)rintf(src[i] * scale);
        q = min(max(q, -32640), 32639);
        int d1 = (q + 128) >> 8;
        int d0 = q - (d1 << 8);
        dst[i] = (unsigned short)((d0 & 0xFF) | ((d1 & 0xFF) << 8));
    }
}

// ---------------- u GEMM: states[m] = x_in[:,m-1,:] @ W_in^T + b_in ----------------
__global__ __launch_bounds__(256) void u_gemm(
    const unsigned short* __restrict__ x_hi, const unsigned short* __restrict__ x_lo,
    const unsigned short* __restrict__ Win_hi, const unsigned short* __restrict__ Win_lo,
    const float* __restrict__ b_in,
    unsigned short* __restrict__ st_hi, unsigned short* __restrict__ st_lo) {
    const int t = blockIdx.y;            // 0..254 -> m = t+1
    const int r0 = blockIdx.x * 64;
    const int tid = threadIdx.x;
    const int w = tid >> 6, l = tid & 63;
    const int lm = l & 15, lg = l >> 4;

    __shared__ __align__(16) unsigned short Bs[2][64][72];

    f32x4 acc[4][3];
#pragma unroll
    for (int nt = 0; nt < 4; ++nt)
#pragma unroll
        for (int q = 0; q < 3; ++q) acc[nt][q] = (f32x4)0.0f;

    const int ab = w * 16 + lm;
    const long xbase = ((long)ab * T_ + t) * DIN;

    for (int s = 0; s < 8; ++s) {
#pragma unroll
        for (int q = 0; q < 4; ++q) {
            int idx = q * 256 + tid;
            int mt = idx >> 9;
            int rem = idx & 511;
            int row = rem >> 3, k8 = rem & 7;
            const unsigned short* sp =
                (mt ? Win_lo : Win_hi) + (long)(r0 + row) * DIN + s * 64 + k8 * 8;
            *(short8*)&Bs[mt][row][k8 * 8] = *(const short8*)sp;
        }
        __syncthreads();
#pragma unroll
        for (int ki = 0; ki < 2; ++ki) {
            int k = s * 64 + ki * 32 + lg * 8;
            short8 ahi = *(const short8*)&x_hi[xbase + k];
            short8 alo = *(const short8*)&x_lo[xbase + k];
#pragma unroll
            for (int nt = 0; nt < 4; ++nt) {
                short8 bhi = *(const short8*)&Bs[0][nt * 16 + lm][ki * 32 + lg * 8];
                short8 blo = *(const short8*)&Bs[1][nt * 16 + lm][ki * 32 + lg * 8];
                acc[nt][0] = __builtin_amdgcn_mfma_f32_16x16x32_bf16(ahi, bhi, acc[nt][0], 0, 0, 0);
                acc[nt][1] = __builtin_amdgcn_mfma_f32_16x16x32_bf16(ahi, blo, acc[nt][1], 0, 0, 0);
                acc[nt][2] = __builtin_amdgcn_mfma_f32_16x16x32_bf16(alo, bhi, acc[nt][2], 0, 0, 0);
            }
        }
        __syncthreads();
    }
    const int m = t + 1;
#pragma unroll
    for (int nt = 0; nt < 4; ++nt) {
        f32x4 s4 = acc[nt][0] + acc[nt][1] + acc[nt][2];
        int r = r0 + nt * 16 + lm;
        float bias = b_in[r];
#pragma unroll
        for (int j = 0; j < 4; ++j) {
            int bb = w * 16 + lg * 4 + j;
            float v = s4[j] + bias;
            unsigned short h = f2bf(v);
            long o = ((long)m * B_ + bb) * DRES + r;
            st_hi[o] = h;
            st_lo[o] = f2bf(v - bf2f(h));
        }
    }
}

// ---------------- persistent recurrence: fresh-slot h, cached consumer reads ----------------
// 256 WGs x 512 threads. Cluster cl = bid>>6 owns batch [cl*16,+16).
// WG wgl owns W rows [wgl*32,+32) in LDS. Wave ks = K slice of 256, gated on
// flags of the 8 producer WGs x 8 waves (idx ks*64+l). Distributed epilogue.
#define MFI8(a, b, c) __builtin_amdgcn_mfma_i32_16x16x64_i8(a, b, c, 0, 0, 0)
#define PRM(hi, lo, sel) \
    (int)__builtin_amdgcn_perm((unsigned)(hi), (unsigned)(lo), (sel))

__global__ __launch_bounds__(512) void recur_persist(
    const char* __restrict__ wq1, const char* __restrict__ wq0,
    unsigned short* __restrict__ hq,
    unsigned short* __restrict__ st_hi, const unsigned short* __restrict__ st_lo,
    unsigned* __restrict__ bar) {
    extern __shared__ char smem[];           // [0,64K): W1, [64K,128K): W0, [128K,160K): red x2
    float* redf = (float*)(smem + 131072);   // [2][8 waves][2 rt][64 lanes] f32x4
    const int bid = blockIdx.x;
    const int cl  = bid >> 6;
    const int wgl = bid & 63;
    const int gr0 = wgl * 32;
    const int cb0 = cl * 16;
    const int tid = threadIdx.x;
    const int w = tid >> 6, l = tid & 63;
    const int lm = l & 15, lg = l >> 4;
    const int ks = w;                        // K slice (8 x 256)
    const size_t SL = (size_t)B_ * DRES;
    unsigned* prodf = bar + cl * 512;        // [64 wg][8 wave] flags for this cluster

    // one-time agent fence: L2 invalidate -> no stale lines from prior replays
    __threadfence();

    // stage W digit planes once (swizzled 16B chunks; ordinary cached loads)
    for (int c = tid; c < 8192; c += 512) {
        int mat = c >> 12;
        int rem = c & 4095;
        int row = rem >> 7, k16 = rem & 127;
        const char* src = (mat ? wq0 : wq1) + (size_t)(gr0 + row) * DRES + k16 * 16;
        int dst = mat * 65536 + row * 2048 + ((k16 * 16) ^ ((row & 7) << 4));
        *(i32x4*)(smem + dst) = *(const i32x4*)src;
    }
    __syncthreads();

    const int swz = (lm & 7) << 4;
    const int lgo = lg * 16;
    const char* lwr0_1 = smem + lm * 2048;
    const char* lwr0_0 = smem + 65536 + lm * 2048;
    const char* lwr1_1 = smem + (16 + lm) * 2048;
    const char* lwr1_0 = smem + 65536 + (16 + lm) * 2048;

    const unsigned* gatef = prodf + ks * 64 + l;       // producer wave flags (coalesced)
    const unsigned* ownf  = prodf + wgl * 8 + w;       // this wave's own flag

    // distributed-epilogue mapping: lane owns value (eb, er)
    const int rt_s = w & 1, q_s = w >> 1;
    const int eb = cb0 + q_s * 4 + lg;
    const int er = gr0 + rt_s * 16 + lm;
    const float* rbase = redf + (size_t)((rt_s * 64) + q_s * 16 + lm) * 4 + lg;
    const size_t eoff = (size_t)eb * DRES + er;

    for (int m = 1; m < T_; ++m) {
        // u prefetch (plain cached; latency hides under gate/A-load)
        unsigned short uh = st_hi[(size_t)m * SL + eoff];
        unsigned short ul = st_lo[(size_t)m * SL + eoff];

        // per-wave gate: all 64 producer waves have published h_{m-1}.
        // MUST complete before the cached A-loads below (asm memory clobber
        // prevents hoisting) -- first touch of a fresh line is then safe.
        if (m > 1) {
            int it_ = 0;
            while (true) {
                unsigned pv;
                asm volatile("global_load_dword %0, %1, off sc0 sc1" : "=v"(pv) : "v"(gatef));
                asm volatile("s_waitcnt vmcnt(0)" ::: "memory");
                if (__all(pv >= (unsigned)(m - 1))) break;
                if (++it_ > (1 << 18)) break;
                __builtin_amdgcn_s_sleep(1);
            }
        }

        // A loads (packed i16 pairs): PLAIN CACHED loads from fresh slot m-1.
        // L2 miss fills from memory-side L3 (holds producers' sc0sc1 data);
        // co-XCD WGs then hit L2.
        const i32x4* pA = (const i32x4*)((const char*)hq + (size_t)(m - 1) * SLQB
                         + (size_t)(cb0 + lm) * 4096 + ks * 512 + lg * 32);
        i32x4 U[8];
#pragma unroll
        for (int c = 0; c < 4; ++c) {
            U[c * 2]     = pA[c * 8];
            U[c * 2 + 1] = pA[c * 8 + 1];
        }

        i32x4 A11[2], A10[2], A01[2], A00[2];
#pragma unroll
        for (int rt = 0; rt < 2; ++rt) {
            A11[rt] = (i32x4)0; A10[rt] = (i32x4)0; A01[rt] = (i32x4)0; A00[rt] = (i32x4)0;
        }
#pragma unroll
        for (int c = 0; c < 4; ++c) {
            i32x4 v0 = U[c * 2], v1 = U[c * 2 + 1];
            i32x4 ah0, ah1;
            ah0[0] = PRM(v0[1], v0[0], 0x06040200u); ah1[0] = PRM(v0[1], v0[0], 0x07050301u);
            ah0[1] = PRM(v0[3], v0[2], 0x06040200u); ah1[1] = PRM(v0[3], v0[2], 0x07050301u);
            ah0[2] = PRM(v1[1], v1[0], 0x06040200u); ah1[2] = PRM(v1[1], v1[0], 0x07050301u);
            ah0[3] = PRM(v1[3], v1[2], 0x06040200u); ah1[3] = PRM(v1[3], v1[2], 0x07050301u);
            int kbs = (ks * 256 + c * 64 + lgo) ^ swz;
            i32x4 b1a = *(const i32x4*)(lwr0_1 + kbs);
            i32x4 b0a = *(const i32x4*)(lwr0_0 + kbs);
            i32x4 b1b = *(const i32x4*)(lwr1_1 + kbs);
            i32x4 b0b = *(const i32x4*)(lwr1_0 + kbs);
            A11[0] = MFI8(ah1, b1a, A11[0]);
            A10[0] = MFI8(ah1, b0a, A10[0]);
            A01[0] = MFI8(ah0, b1a, A01[0]);
            A00[0] = MFI8(ah0, b0a, A00[0]);
            A11[1] = MFI8(ah1, b1b, A11[1]);
            A10[1] = MFI8(ah1, b0b, A10[1]);
            A01[1] = MFI8(ah0, b1b, A01[1]);
            A00[1] = MFI8(ah0, b0b, A00[1]);
        }
        f32x4 pf[2];
#pragma unroll
        for (int rt = 0; rt < 2; ++rt)
#pragma unroll
            for (int j = 0; j < 4; ++j)
                pf[rt][j] = 65536.f * (float)A11[rt][j]
                          + 256.f * (float)(A10[rt][j] + A01[rt][j])
                          + (float)A00[rt][j];
        // publish partials into red[m&1]
        float* rw = redf + (size_t)(m & 1) * 4096;
        *(f32x4*)(rw + (size_t)((w * 2 + 0) * 64 + l) * 4) = pf[0];
        *(f32x4*)(rw + (size_t)((w * 2 + 1) * 64 + l) * 4) = pf[1];
        __syncthreads();   // the ONLY barrier per step (red dbuf protects reuse)

        // distributed epilogue: every lane reduces + activates its one value
        const float* rb = rbase + (size_t)(m & 1) * 4096;
        float s = 0.f;
#pragma unroll
        for (int p = 0; p < 8; ++p) s += rb[(size_t)p * 512];
        float pre = s * 0x1p-30f + bf2f(uh) + bf2f(ul);
        float ex = __expf(2.f * pre);
        float h = 1.f - 2.f * __builtin_amdgcn_rcpf(ex + 1.f);
        if (m < T_ - 1) {
            int q = (int)rintf(h * 16384.f);
            int d1 = (q + 128) >> 8;
            int d0 = q - (d1 << 8);
            unsigned pk = (unsigned)(d0 & 0xFF) | ((unsigned)(d1 & 0xFF) << 8);
            const unsigned short* dst = hq + (size_t)m * SLP + eoff;
            asm volatile("global_store_short %0, %1, off sc0 sc1"
                         :: "v"(dst), "v"(pk) : "memory");
            // per-wave release: drain own stores, then publish this wave's flag
            asm volatile("s_waitcnt vmcnt(0)" ::: "memory");
            if (l == 0) {
                unsigned mv = (unsigned)m;
                asm volatile("global_store_dword %0, %1, off sc0 sc1"
                             :: "v"(ownf), "v"(mv) : "memory");
            }
        }
        st_hi[(size_t)m * SL + eoff] = f2bf(h);   // bf16 state for readout (cached)
    }
}

// ---------------- readout: out[b][t][o] = states[t][b][:] . W_out[o][:] + b_out ----------------
__global__ __launch_bounds__(256) void readout_kern(
    const unsigned short* __restrict__ st_hi,
    const unsigned short* __restrict__ Wout_hi,
    const float* __restrict__ b_out, float* __restrict__ out) {
    const int n0 = blockIdx.x * 128;
    const int row0 = blockIdx.y * 64;
    const int tid = threadIdx.x;
    const int w = tid >> 6, l = tid & 63;
    const int lm = l & 15, lg = l >> 4;

    __shared__ __align__(16) unsigned short Bs[128][72];

    f32x4 acc[8];
#pragma unroll
    for (int nt = 0; nt < 8; ++nt) acc[nt] = (f32x4)0.f;

    const int row = row0 + w * 16 + lm;
    const long abase = (long)row * DRES;

    for (int s = 0; s < 32; ++s) {
#pragma unroll
        for (int q = 0; q < 4; ++q) {
            int idx = q * 256 + tid;
            int r_ = idx >> 3, k8 = idx & 7;
            *(short8*)&Bs[r_][k8 * 8] =
                *(const short8*)(Wout_hi + (long)(n0 + r_) * DRES + s * 64 + k8 * 8);
        }
        __syncthreads();
#pragma unroll
        for (int ki = 0; ki < 2; ++ki) {
            short8 a = *(const short8*)&st_hi[abase + s * 64 + ki * 32 + lg * 8];
#pragma unroll
            for (int nt = 0; nt < 8; ++nt) {
                short8 bf = *(const short8*)&Bs[nt * 16 + lm][ki * 32 + lg * 8];
                acc[nt] = __builtin_amdgcn_mfma_f32_16x16x32_bf16(a, bf, acc[nt], 0, 0, 0);
            }
        }
        __syncthreads();
    }
#pragma unroll
    for (int nt = 0; nt < 8; ++nt) {
        int o = n0 + nt * 16 + lm;
        float bias = b_out[o];
#pragma unroll
        for (int j = 0; j < 4; ++j) {
            int rr = row0 + w * 16 + lg * 4 + j;
            int t = rr >> 6, bb = rr & 63;
            out[((long)bb * T_ + t) * DOUT + o] = acc[nt][j] + bias;
        }
    }
}

extern "C" void kernel_launch(void* const* d_in, const int* in_sizes, int n_in,
                              void* d_out, int out_size, void* d_ws, size_t ws_size,
                              hipStream_t stream) {
    const float* x_res_init = (const float*)d_in[0];
    const float* x_in       = (const float*)d_in[1];
    const float* W_in       = (const float*)d_in[2];
    const float* b_in       = (const float*)d_in[3];
    const float* W_res      = (const float*)d_in[4];
    const float* W_out      = (const float*)d_in[5];
    const float* b_out      = (const float*)d_in[6];
    float* out = (float*)d_out;

    char* p = (char*)d_ws;
    auto alloc = [&](size_t bytes) -> char* {
        char* r = p;
        p += (bytes + 255) & ~(size_t)255;
        return r;
    };
    const size_t SL = (size_t)B_ * DRES;
    unsigned short* st_hi   = (unsigned short*)alloc((size_t)T_ * SL * 2);
    unsigned short* st_lo   = (unsigned short*)alloc((size_t)T_ * SL * 2);
    char*           wq1     = alloc((size_t)DRES * DRES);
    char*           wq0     = alloc((size_t)DRES * DRES);
    unsigned short* hq      = (unsigned short*)alloc((size_t)T_ * SLQB);  // fresh slot/step
    unsigned short* Win_hi  = (unsigned short*)alloc((size_t)DRES * DIN * 2);
    unsigned short* Win_lo  = (unsigned short*)alloc((size_t)DRES * DIN * 2);
    unsigned short* Wout_hi = (unsigned short*)alloc((size_t)DOUT * DRES * 2);
    unsigned short* Wout_lo = (unsigned short*)alloc((size_t)DOUT * DRES * 2);
    unsigned short* x_hi    = (unsigned short*)alloc((size_t)B_ * T_ * DIN * 2);
    unsigned short* x_lo    = (unsigned short*)alloc((size_t)B_ * T_ * DIN * 2);
    unsigned*       bar     = (unsigned*)alloc(8192);   // 4 clusters x 64 wg x 8 waves

    hipMemsetAsync(bar, 0, 8192, stream);   // flags are per-launch monotonic

    auto launch_split = [&](const float* src, unsigned short* hi, unsigned short* lo, size_t n) {
        int n4 = (int)(n / 4);
        int blocks = (n4 + 255) / 256;
        if (blocks > 2048) blocks = 2048;
        split4_kern<<<blocks, 256, 0, stream>>>((const float4*)src, (ushort4*)hi, (ushort4*)lo, n4);
    };
    launch_split(W_in,  Win_hi,  Win_lo,  (size_t)DRES * DIN);
    launch_split(W_out, Wout_hi, Wout_lo, (size_t)DOUT * DRES);
    launch_split(x_in,  x_hi,    x_lo,    (size_t)B_ * T_ * DIN);
    launch_split(x_res_init, st_hi, st_lo, SL);   // states[0] (bf16, for readout)

    // quantize W_res (two i8 planes, scale 2^16) and h_0 (packed i16, slot 0)
    quant_kern<<<2048, 256, 0, stream>>>(W_res, 65536.f, wq1, wq0, DRES * DRES);
    quantp_kern<<<512, 256, 0, stream>>>(x_res_init, 16384.f, hq, B_ * DRES);

    // u into states[1..255]
    u_gemm<<<dim3(32, T_ - 1), 256, 0, stream>>>(x_hi, x_lo, Win_hi, Win_lo, b_in, st_hi, st_lo);

    // persistent recurrence: 256 WGs x 512 threads (4 clusters x 64 WGs), 160 KiB LDS
    const size_t shmem = 131072 + 2 * 4096 * sizeof(float);   // W planes + red x2 = 163840
    hipFuncSetAttribute(reinterpret_cast<const void*>(recur_persist),
                        hipFuncAttributeMaxDynamicSharedMemorySize, (int)shmem);
    void* kargs[] = { (void*)&wq1, (void*)&wq0, (void*)&hq,
                      (void*)&st_hi, (void*)&st_lo, (void*)&bar };
    hipLaunchCooperativeKernel((const void*)recur_persist, dim3(256), dim3(512),
                               kargs, (unsigned int)shmem, stream);

    // readout
    readout_kern<<<dim3(4, 256), 256, 0, stream>>>(st_hi, Wout_hi, b_out, out);
}

// Round 16
// 1768.337 us; speedup vs baseline: 1.0286x; 1.0286x over previous
//
#include <hip/hip_runtime.h>
#include <hip/hip_bf16.h>

// ESN: h_m = tanh(W_res h_{m-1} + W_in x_{m-1} + b_in), readout on all states.
// Recurrence: 4 independent batch-clusters of 64 WGs (full W_res copy per
// cluster in aggregate LDS as i8 digit planes). h as packed i16 digit pairs
// (d0|d1<<8) in a 4-slot global ring via sc0 sc1. PER-WAVE producer flags;
// SPLIT gate (poll 4 WGs -> load half -> poll 4 WGs -> load half) overlaps
// poll RTT with A-load flight. Double-buffered LDS reduction -> one
// syncthreads/step. Distributed epilogue (every lane owns one output).
// mfma_i32_16x16x64_i8, all 4 digit products -> exact integer GEMM.

#define B_   64
#define T_   256
#define DIN  512
#define DRES 2048
#define DOUT 512
#define SLP  131072   // elements per packed-h slot (B*DRES)
#define SLQB 262144   // bytes per packed-h slot

typedef __attribute__((ext_vector_type(8))) short short8;
typedef __attribute__((ext_vector_type(4))) float f32x4;
typedef __attribute__((ext_vector_type(4))) int i32x4;

__device__ __forceinline__ unsigned short f2bf(float x) {
    unsigned int u = __float_as_uint(x);
    unsigned int r = u + 0x7fffu + ((u >> 16) & 1u);
    return (unsigned short)(r >> 16);
}
__device__ __forceinline__ float bf2f(unsigned short h) {
    return __uint_as_float(((unsigned int)h) << 16);
}

// ---------------- split f32 -> bf16 hi/lo ----------------
__global__ void split4_kern(const float4* __restrict__ src,
                            ushort4* __restrict__ hi, ushort4* __restrict__ lo, int n4) {
    int i = blockIdx.x * blockDim.x + threadIdx.x;
    int st = gridDim.x * blockDim.x;
    for (; i < n4; i += st) {
        float4 v = src[i];
        ushort4 h, l;
        h.x = f2bf(v.x); l.x = f2bf(v.x - bf2f(h.x));
        h.y = f2bf(v.y); l.y = f2bf(v.y - bf2f(h.y));
        h.z = f2bf(v.z); l.z = f2bf(v.z - bf2f(h.z));
        h.w = f2bf(v.w); l.w = f2bf(v.w - bf2f(h.w));
        hi[i] = h; lo[i] = l;
    }
}

// ---------------- quantize f32 -> two signed-i8 digit planes (for W) ----------------
__global__ void quant_kern(const float* __restrict__ src, float scale,
                           char* __restrict__ d1, char* __restrict__ d0, int n) {
    int i = blockIdx.x * blockDim.x + threadIdx.x;
    int st = gridDim.x * blockDim.x;
    for (; i < n; i += st) {
        int q = (int)rintf(src[i] * scale);
        q = min(max(q, -32640), 32639);
        int h1 = (q + 128) >> 8;
        d1[i] = (char)h1;
        d0[i] = (char)(q - (h1 << 8));
    }
}

// ---------------- quantize f32 -> packed i16 digit pair (for h_0) ----------------
__global__ void quantp_kern(const float* __restrict__ src, float scale,
                            unsigned short* __restrict__ dst, int n) {
    int i = blockIdx.x * blockDim.x + threadIdx.x;
    int st = gridDim.x * blockDim.x;
    for (; i < n; i += st) {
        int q = (int)rintf(src[i] * scale);
        q = min(max(q, -32640), 32639);
        int d1 = (q + 128) >> 8;
        int d0 = q - (d1 << 8);
        dst[i] = (unsigned short)((d0 & 0xFF) | ((d1 & 0xFF) << 8));
    }
}

// ---------------- u GEMM: states[m] = x_in[:,m-1,:] @ W_in^T + b_in ----------------
__global__ __launch_bounds__(256) void u_gemm(
    const unsigned short* __restrict__ x_hi, const unsigned short* __restrict__ x_lo,
    const unsigned short* __restrict__ Win_hi, const unsigned short* __restrict__ Win_lo,
    const float* __restrict__ b_in,
    unsigned short* __restrict__ st_hi, unsigned short* __restrict__ st_lo) {
    const int t = blockIdx.y;            // 0..254 -> m = t+1
    const int r0 = blockIdx.x * 64;
    const int tid = threadIdx.x;
    const int w = tid >> 6, l = tid & 63;
    const int lm = l & 15, lg = l >> 4;

    __shared__ __align__(16) unsigned short Bs[2][64][72];

    f32x4 acc[4][3];
#pragma unroll
    for (int nt = 0; nt < 4; ++nt)
#pragma unroll
        for (int q = 0; q < 3; ++q) acc[nt][q] = (f32x4)0.0f;

    const int ab = w * 16 + lm;
    const long xbase = ((long)ab * T_ + t) * DIN;

    for (int s = 0; s < 8; ++s) {
#pragma unroll
        for (int q = 0; q < 4; ++q) {
            int idx = q * 256 + tid;
            int mt = idx >> 9;
            int rem = idx & 511;
            int row = rem >> 3, k8 = rem & 7;
            const unsigned short* sp =
                (mt ? Win_lo : Win_hi) + (long)(r0 + row) * DIN + s * 64 + k8 * 8;
            *(short8*)&Bs[mt][row][k8 * 8] = *(const short8*)sp;
        }
        __syncthreads();
#pragma unroll
        for (int ki = 0; ki < 2; ++ki) {
            int k = s * 64 + ki * 32 + lg * 8;
            short8 ahi = *(const short8*)&x_hi[xbase + k];
            short8 alo = *(const short8*)&x_lo[xbase + k];
#pragma unroll
            for (int nt = 0; nt < 4; ++nt) {
                short8 bhi = *(const short8*)&Bs[0][nt * 16 + lm][ki * 32 + lg * 8];
                short8 blo = *(const short8*)&Bs[1][nt * 16 + lm][ki * 32 + lg * 8];
                acc[nt][0] = __builtin_amdgcn_mfma_f32_16x16x32_bf16(ahi, bhi, acc[nt][0], 0, 0, 0);
                acc[nt][1] = __builtin_amdgcn_mfma_f32_16x16x32_bf16(ahi, blo, acc[nt][1], 0, 0, 0);
                acc[nt][2] = __builtin_amdgcn_mfma_f32_16x16x32_bf16(alo, bhi, acc[nt][2], 0, 0, 0);
            }
        }
        __syncthreads();
    }
    const int m = t + 1;
#pragma unroll
    for (int nt = 0; nt < 4; ++nt) {
        f32x4 s4 = acc[nt][0] + acc[nt][1] + acc[nt][2];
        int r = r0 + nt * 16 + lm;
        float bias = b_in[r];
#pragma unroll
        for (int j = 0; j < 4; ++j) {
            int bb = w * 16 + lg * 4 + j;
            float v = s4[j] + bias;
            unsigned short h = f2bf(v);
            long o = ((long)m * B_ + bb) * DRES + r;
            st_hi[o] = h;
            st_lo[o] = f2bf(v - bf2f(h));
        }
    }
}

// ---------------- persistent recurrence: per-wave flags, split gate ----------------
// 256 WGs x 512 threads. Cluster cl = bid>>6 owns batch [cl*16,+16).
// WG wgl owns W rows [wgl*32,+32) in LDS. Wave ks = K slice of 256, gated on
// flags of the 8 producer WGs x 8 waves (idx ks*64+l). Distributed epilogue.
#define MFI8(a, b, c) __builtin_amdgcn_mfma_i32_16x16x64_i8(a, b, c, 0, 0, 0)
#define PRM(hi, lo, sel) \
    (int)__builtin_amdgcn_perm((unsigned)(hi), (unsigned)(lo), (sel))

__global__ __launch_bounds__(512) void recur_persist(
    const char* __restrict__ wq1, const char* __restrict__ wq0,
    unsigned short* __restrict__ hq,
    unsigned short* __restrict__ st_hi, const unsigned short* __restrict__ st_lo,
    unsigned* __restrict__ bar) {
    extern __shared__ char smem[];           // [0,64K): W1, [64K,128K): W0, [128K,160K): red x2
    float* redf = (float*)(smem + 131072);   // [2][8 waves][2 rt][64 lanes] f32x4
    const int bid = blockIdx.x;
    const int cl  = bid >> 6;
    const int wgl = bid & 63;
    const int gr0 = wgl * 32;
    const int cb0 = cl * 16;
    const int tid = threadIdx.x;
    const int w = tid >> 6, l = tid & 63;
    const int lm = l & 15, lg = l >> 4;
    const int ks = w;                        // K slice (8 x 256)
    const size_t SL = (size_t)B_ * DRES;
    unsigned* prodf = bar + cl * 512;        // [64 wg][8 wave] flags for this cluster

    // stage W digit planes once (swizzled 16B chunks; ordinary cached loads)
    for (int c = tid; c < 8192; c += 512) {
        int mat = c >> 12;
        int rem = c & 4095;
        int row = rem >> 7, k16 = rem & 127;
        const char* src = (mat ? wq0 : wq1) + (size_t)(gr0 + row) * DRES + k16 * 16;
        int dst = mat * 65536 + row * 2048 + ((k16 * 16) ^ ((row & 7) << 4));
        *(i32x4*)(smem + dst) = *(const i32x4*)src;
    }
    __syncthreads();

    const int swz = (lm & 7) << 4;
    const int lgo = lg * 16;
    const char* lwr0_1 = smem + lm * 2048;
    const char* lwr0_0 = smem + 65536 + lm * 2048;
    const char* lwr1_1 = smem + (16 + lm) * 2048;
    const char* lwr1_0 = smem + 65536 + (16 + lm) * 2048;

    const unsigned* gatef = prodf + ks * 64 + l;       // producer wave flags (coalesced)
    unsigned* ownf = prodf + wgl * 8 + w;              // this wave's own flag

    // distributed-epilogue mapping: lane owns value (eb, er)
    const int rt_s = w & 1, q_s = w >> 1;
    const int eb = cb0 + q_s * 4 + lg;
    const int er = gr0 + rt_s * 16 + lm;
    const float* rbase = redf + (size_t)((rt_s * 64) + q_s * 16 + lm) * 4 + lg;
    const size_t eoff = (size_t)eb * DRES + er;

    for (int m = 1; m < T_; ++m) {
        // u prefetch (plain cached; latency hides under gate/A-load)
        unsigned short uh = st_hi[(size_t)m * SL + eoff];
        unsigned short ul = st_lo[(size_t)m * SL + eoff];

        const char* pA = (const char*)hq + (size_t)((m - 1) & 3) * SLQB
                       + (size_t)(cb0 + lm) * 4096 + ks * 512 + lg * 32;
        i32x4 U[8];

        // --- split gate: first 4 producer WGs (lanes 0..31 of gatef) ---
        if (m > 1) {
            int it_ = 0;
            while (true) {
                unsigned pv;
                asm volatile("global_load_dword %0, %1, off sc0 sc1" : "=v"(pv) : "v"(gatef));
                asm volatile("s_waitcnt vmcnt(0)" ::: "memory");
                if (__all((l >= 32) || (pv >= (unsigned)(m - 1)))) break;
                if (++it_ > (1 << 18)) break;
                __builtin_amdgcn_s_sleep(1);
            }
        }
        // K rows [ks*256, +128) = rows of WGs ks*8..ks*8+3 -> c = 0,1
#pragma unroll
        for (int c = 0; c < 2; ++c) {
            asm volatile("global_load_dwordx4 %0, %1, off sc0 sc1"
                         : "=v"(U[c * 2]) : "v"(pA + c * 128));
            asm volatile("global_load_dwordx4 %0, %1, off sc0 sc1"
                         : "=v"(U[c * 2 + 1]) : "v"(pA + c * 128 + 16));
        }
        // --- second half gate (c01 loads stay in flight during the poll) ---
        if (m > 1) {
            int it_ = 0;
            while (true) {
                unsigned pv;
                asm volatile("global_load_dword %0, %1, off sc0 sc1" : "=v"(pv) : "v"(gatef));
                asm volatile("s_waitcnt vmcnt(0)" ::: "memory");
                if (__all((l < 32) || (pv >= (unsigned)(m - 1)))) break;
                if (++it_ > (1 << 18)) break;
                __builtin_amdgcn_s_sleep(1);
            }
        }
#pragma unroll
        for (int c = 2; c < 4; ++c) {
            asm volatile("global_load_dwordx4 %0, %1, off sc0 sc1"
                         : "=v"(U[c * 2]) : "v"(pA + c * 128));
            asm volatile("global_load_dwordx4 %0, %1, off sc0 sc1"
                         : "=v"(U[c * 2 + 1]) : "v"(pA + c * 128 + 16));
        }
        asm volatile("s_waitcnt vmcnt(0)" ::: "memory");
        __builtin_amdgcn_sched_barrier(0);

        i32x4 A11[2], A10[2], A01[2], A00[2];
#pragma unroll
        for (int rt = 0; rt < 2; ++rt) {
            A11[rt] = (i32x4)0; A10[rt] = (i32x4)0; A01[rt] = (i32x4)0; A00[rt] = (i32x4)0;
        }
#pragma unroll
        for (int c = 0; c < 4; ++c) {
            i32x4 v0 = U[c * 2], v1 = U[c * 2 + 1];
            i32x4 ah0, ah1;
            ah0[0] = PRM(v0[1], v0[0], 0x06040200u); ah1[0] = PRM(v0[1], v0[0], 0x07050301u);
            ah0[1] = PRM(v0[3], v0[2], 0x06040200u); ah1[1] = PRM(v0[3], v0[2], 0x07050301u);
            ah0[2] = PRM(v1[1], v1[0], 0x06040200u); ah1[2] = PRM(v1[1], v1[0], 0x07050301u);
            ah0[3] = PRM(v1[3], v1[2], 0x06040200u); ah1[3] = PRM(v1[3], v1[2], 0x07050301u);
            int kbs = (ks * 256 + c * 64 + lgo) ^ swz;
            i32x4 b1a = *(const i32x4*)(lwr0_1 + kbs);
            i32x4 b0a = *(const i32x4*)(lwr0_0 + kbs);
            i32x4 b1b = *(const i32x4*)(lwr1_1 + kbs);
            i32x4 b0b = *(const i32x4*)(lwr1_0 + kbs);
            A11[0] = MFI8(ah1, b1a, A11[0]);
            A10[0] = MFI8(ah1, b0a, A10[0]);
            A01[0] = MFI8(ah0, b1a, A01[0]);
            A00[0] = MFI8(ah0, b0a, A00[0]);
            A11[1] = MFI8(ah1, b1b, A11[1]);
            A10[1] = MFI8(ah1, b0b, A10[1]);
            A01[1] = MFI8(ah0, b1b, A01[1]);
            A00[1] = MFI8(ah0, b0b, A00[1]);
        }
        f32x4 pf[2];
#pragma unroll
        for (int rt = 0; rt < 2; ++rt)
#pragma unroll
            for (int j = 0; j < 4; ++j)
                pf[rt][j] = 65536.f * (float)A11[rt][j]
                          + 256.f * (float)(A10[rt][j] + A01[rt][j])
                          + (float)A00[rt][j];
        // publish partials into red[m&1]
        float* rw = redf + (size_t)(m & 1) * 4096;
        *(f32x4*)(rw + (size_t)((w * 2 + 0) * 64 + l) * 4) = pf[0];
        *(f32x4*)(rw + (size_t)((w * 2 + 1) * 64 + l) * 4) = pf[1];
        __syncthreads();   // the ONLY barrier per step (red dbuf protects reuse)

        // distributed epilogue: every lane reduces + activates its one value
        const float* rb = rbase + (size_t)(m & 1) * 4096;
        float s = 0.f;
#pragma unroll
        for (int p = 0; p < 8; ++p) s += rb[(size_t)p * 512];
        float pre = s * 0x1p-30f + bf2f(uh) + bf2f(ul);
        float ex = __expf(2.f * pre);
        float h = 1.f - 2.f * __builtin_amdgcn_rcpf(ex + 1.f);
        if (m < T_ - 1) {
            int q = (int)rintf(h * 16384.f);
            int d1 = (q + 128) >> 8;
            int d0 = q - (d1 << 8);
            unsigned pk = (unsigned)(d0 & 0xFF) | ((unsigned)(d1 & 0xFF) << 8);
            const unsigned short* dst = hq + (size_t)(m & 3) * SLP + eoff;
            asm volatile("global_store_short %0, %1, off sc0 sc1"
                         :: "v"(dst), "v"(pk) : "memory");
            // per-wave release: drain own stores, then publish this wave's flag
            asm volatile("s_waitcnt vmcnt(0)" ::: "memory");
            if (l == 0) {
                unsigned mv = (unsigned)m;
                asm volatile("global_store_dword %0, %1, off sc0 sc1"
                             :: "v"(ownf), "v"(mv) : "memory");
            }
        }
        st_hi[(size_t)m * SL + eoff] = f2bf(h);   // bf16 state for readout (cached)
    }
}

// ---------------- readout: out[b][t][o] = states[t][b][:] . W_out[o][:] + b_out ----------------
__global__ __launch_bounds__(256) void readout_kern(
    const unsigned short* __restrict__ st_hi,
    const unsigned short* __restrict__ Wout_hi,
    const float* __restrict__ b_out, float* __restrict__ out) {
    const int n0 = blockIdx.x * 128;
    const int row0 = blockIdx.y * 64;
    const int tid = threadIdx.x;
    const int w = tid >> 6, l = tid & 63;
    const int lm = l & 15, lg = l >> 4;

    __shared__ __align__(16) unsigned short Bs[128][72];

    f32x4 acc[8];
#pragma unroll
    for (int nt = 0; nt < 8; ++nt) acc[nt] = (f32x4)0.f;

    const int row = row0 + w * 16 + lm;
    const long abase = (long)row * DRES;

    for (int s = 0; s < 32; ++s) {
#pragma unroll
        for (int q = 0; q < 4; ++q) {
            int idx = q * 256 + tid;
            int r_ = idx >> 3, k8 = idx & 7;
            *(short8*)&Bs[r_][k8 * 8] =
                *(const short8*)(Wout_hi + (long)(n0 + r_) * DRES + s * 64 + k8 * 8);
        }
        __syncthreads();
#pragma unroll
        for (int ki = 0; ki < 2; ++ki) {
            short8 a = *(const short8*)&st_hi[abase + s * 64 + ki * 32 + lg * 8];
#pragma unroll
            for (int nt = 0; nt < 8; ++nt) {
                short8 bf = *(const short8*)&Bs[nt * 16 + lm][ki * 32 + lg * 8];
                acc[nt] = __builtin_amdgcn_mfma_f32_16x16x32_bf16(a, bf, acc[nt], 0, 0, 0);
            }
        }
        __syncthreads();
    }
#pragma unroll
    for (int nt = 0; nt < 8; ++nt) {
        int o = n0 + nt * 16 + lm;
        float bias = b_out[o];
#pragma unroll
        for (int j = 0; j < 4; ++j) {
            int rr = row0 + w * 16 + lg * 4 + j;
            int t = rr >> 6, bb = rr & 63;
            out[((long)bb * T_ + t) * DOUT + o] = acc[nt][j] + bias;
        }
    }
}

extern "C" void kernel_launch(void* const* d_in, const int* in_sizes, int n_in,
                              void* d_out, int out_size, void* d_ws, size_t ws_size,
                              hipStream_t stream) {
    const float* x_res_init = (const float*)d_in[0];
    const float* x_in       = (const float*)d_in[1];
    const float* W_in       = (const float*)d_in[2];
    const float* b_in       = (const float*)d_in[3];
    const float* W_res      = (const float*)d_in[4];
    const float* W_out      = (const float*)d_in[5];
    const float* b_out      = (const float*)d_in[6];
    float* out = (float*)d_out;

    char* p = (char*)d_ws;
    auto alloc = [&](size_t bytes) -> char* {
        char* r = p;
        p += (bytes + 255) & ~(size_t)255;
        return r;
    };
    const size_t SL = (size_t)B_ * DRES;
    unsigned short* st_hi   = (unsigned short*)alloc((size_t)T_ * SL * 2);
    unsigned short* st_lo   = (unsigned short*)alloc((size_t)T_ * SL * 2);
    char*           wq1     = alloc((size_t)DRES * DRES);
    char*           wq0     = alloc((size_t)DRES * DRES);
    unsigned short* hq      = (unsigned short*)alloc(4 * (size_t)SLQB);
    unsigned short* Win_hi  = (unsigned short*)alloc((size_t)DRES * DIN * 2);
    unsigned short* Win_lo  = (unsigned short*)alloc((size_t)DRES * DIN * 2);
    unsigned short* Wout_hi = (unsigned short*)alloc((size_t)DOUT * DRES * 2);
    unsigned short* Wout_lo = (unsigned short*)alloc((size_t)DOUT * DRES * 2);
    unsigned short* x_hi    = (unsigned short*)alloc((size_t)B_ * T_ * DIN * 2);
    unsigned short* x_lo    = (unsigned short*)alloc((size_t)B_ * T_ * DIN * 2);
    unsigned*       bar     = (unsigned*)alloc(8192);   // 4 clusters x 64 wg x 8 waves

    hipMemsetAsync(bar, 0, 8192, stream);   // flags are per-launch monotonic

    auto launch_split = [&](const float* src, unsigned short* hi, unsigned short* lo, size_t n) {
        int n4 = (int)(n / 4);
        int blocks = (n4 + 255) / 256;
        if (blocks > 2048) blocks = 2048;
        split4_kern<<<blocks, 256, 0, stream>>>((const float4*)src, (ushort4*)hi, (ushort4*)lo, n4);
    };
    launch_split(W_in,  Win_hi,  Win_lo,  (size_t)DRES * DIN);
    launch_split(W_out, Wout_hi, Wout_lo, (size_t)DOUT * DRES);
    launch_split(x_in,  x_hi,    x_lo,    (size_t)B_ * T_ * DIN);
    launch_split(x_res_init, st_hi, st_lo, SL);   // states[0] (bf16, for readout)

    // quantize W_res (two i8 planes, scale 2^16) and h_0 (packed i16, slot 0)
    quant_kern<<<2048, 256, 0, stream>>>(W_res, 65536.f, wq1, wq0, DRES * DRES);
    quantp_kern<<<512, 256, 0, stream>>>(x_res_init, 16384.f, hq, B_ * DRES);

    // u into states[1..255]
    u_gemm<<<dim3(32, T_ - 1), 256, 0, stream>>>(x_hi, x_lo, Win_hi, Win_lo, b_in, st_hi, st_lo);

    // persistent recurrence: 256 WGs x 512 threads (4 clusters x 64 WGs), 160 KiB LDS
    const size_t shmem = 131072 + 2 * 4096 * sizeof(float);   // W planes + red x2 = 163840
    hipFuncSetAttribute(reinterpret_cast<const void*>(recur_persist),
                        hipFuncAttributeMaxDynamicSharedMemorySize, (int)shmem);
    void* kargs[] = { (void*)&wq1, (void*)&wq0, (void*)&hq,
                      (void*)&st_hi, (void*)&st_lo, (void*)&bar };
    hipLaunchCooperativeKernel((const void*)recur_persist, dim3(256), dim3(512),
                               kargs, (unsigned int)shmem, stream);

    // readout
    readout_kern<<<dim3(4, 256), 256, 0, stream>>>(st_hi, Wout_hi, b_out, out);
}

// Round 17
// 1726.083 us; speedup vs baseline: 1.0538x; 1.0245x over previous
//
#include <hip/hip_runtime.h>
#include <hip/hip_bf16.h>

// ESN: h_m = tanh(W_res h_{m-1} + W_in x_{m-1} + b_in), readout on all states.
// Recurrence: 8 independent batch-clusters of 32 WGs (8 batch each). WG owns
// 64 W rows: hi i8 plane in LDS (128KB, swizzled), lo i8 plane in VGPRs
// (wave's K-window). h as packed i16 digit pairs in a 4-slot global ring via
// sc0 sc1 (proven L3 path). Per-wave producer flags (32 WG x 8 waves); wave
// ks gates on its 4 producer WGs (32 flags, one coalesced poll). One
// syncthreads/step + red dbuf; distributed epilogue (lane owns one output).
// mfma_i32_16x16x64_i8, all 4 digit products -> exact integer GEMM.

#define B_   64
#define T_   256
#define DIN  512
#define DRES 2048
#define DOUT 512
#define SLP  131072   // elements per packed-h slot (B*DRES)
#define SLQB 262144   // bytes per packed-h slot

typedef __attribute__((ext_vector_type(8))) short short8;
typedef __attribute__((ext_vector_type(4))) float f32x4;
typedef __attribute__((ext_vector_type(4))) int i32x4;

__device__ __forceinline__ unsigned short f2bf(float x) {
    unsigned int u = __float_as_uint(x);
    unsigned int r = u + 0x7fffu + ((u >> 16) & 1u);
    return (unsigned short)(r >> 16);
}
__device__ __forceinline__ float bf2f(unsigned short h) {
    return __uint_as_float(((unsigned int)h) << 16);
}

// ---------------- split f32 -> bf16 hi/lo ----------------
__global__ void split4_kern(const float4* __restrict__ src,
                            ushort4* __restrict__ hi, ushort4* __restrict__ lo, int n4) {
    int i = blockIdx.x * blockDim.x + threadIdx.x;
    int st = gridDim.x * blockDim.x;
    for (; i < n4; i += st) {
        float4 v = src[i];
        ushort4 h, l;
        h.x = f2bf(v.x); l.x = f2bf(v.x - bf2f(h.x));
        h.y = f2bf(v.y); l.y = f2bf(v.y - bf2f(h.y));
        h.z = f2bf(v.z); l.z = f2bf(v.z - bf2f(h.z));
        h.w = f2bf(v.w); l.w = f2bf(v.w - bf2f(h.w));
        hi[i] = h; lo[i] = l;
    }
}

// ---------------- quantize f32 -> two signed-i8 digit planes (for W) ----------------
__global__ void quant_kern(const float* __restrict__ src, float scale,
                           char* __restrict__ d1, char* __restrict__ d0, int n) {
    int i = blockIdx.x * blockDim.x + threadIdx.x;
    int st = gridDim.x * blockDim.x;
    for (; i < n; i += st) {
        int q = (int)rintf(src[i] * scale);
        q = min(max(q, -32640), 32639);
        int h1 = (q + 128) >> 8;
        d1[i] = (char)h1;
        d0[i] = (char)(q - (h1 << 8));
    }
}

// ---------------- quantize f32 -> packed i16 digit pair (for h_0) ----------------
__global__ void quantp_kern(const float* __restrict__ src, float scale,
                            unsigned short* __restrict__ dst, int n) {
    int i = blockIdx.x * blockDim.x + threadIdx.x;
    int st = gridDim.x * blockDim.x;
    for (; i < n; i += st) {
        int q = (int)rintf(src[i] * scale);
        q = min(max(q, -32640), 32639);
        int d1 = (q + 128) >> 8;
        int d0 = q - (d1 << 8);
        dst[i] = (unsigned short)((d0 & 0xFF) | ((d1 & 0xFF) << 8));
    }
}

// ---------------- u GEMM: states[m] = x_in[:,m-1,:] @ W_in^T + b_in ----------------
__global__ __launch_bounds__(256) void u_gemm(
    const unsigned short* __restrict__ x_hi, const unsigned short* __restrict__ x_lo,
    const unsigned short* __restrict__ Win_hi, const unsigned short* __restrict__ Win_lo,
    const float* __restrict__ b_in,
    unsigned short* __restrict__ st_hi, unsigned short* __restrict__ st_lo) {
    const int t = blockIdx.y;            // 0..254 -> m = t+1
    const int r0 = blockIdx.x * 64;
    const int tid = threadIdx.x;
    const int w = tid >> 6, l = tid & 63;
    const int lm = l & 15, lg = l >> 4;

    __shared__ __align__(16) unsigned short Bs[2][64][72];

    f32x4 acc[4][3];
#pragma unroll
    for (int nt = 0; nt < 4; ++nt)
#pragma unroll
        for (int q = 0; q < 3; ++q) acc[nt][q] = (f32x4)0.0f;

    const int ab = w * 16 + lm;
    const long xbase = ((long)ab * T_ + t) * DIN;

    for (int s = 0; s < 8; ++s) {
#pragma unroll
        for (int q = 0; q < 4; ++q) {
            int idx = q * 256 + tid;
            int mt = idx >> 9;
            int rem = idx & 511;
            int row = rem >> 3, k8 = rem & 7;
            const unsigned short* sp =
                (mt ? Win_lo : Win_hi) + (long)(r0 + row) * DIN + s * 64 + k8 * 8;
            *(short8*)&Bs[mt][row][k8 * 8] = *(const short8*)sp;
        }
        __syncthreads();
#pragma unroll
        for (int ki = 0; ki < 2; ++ki) {
            int k = s * 64 + ki * 32 + lg * 8;
            short8 ahi = *(const short8*)&x_hi[xbase + k];
            short8 alo = *(const short8*)&x_lo[xbase + k];
#pragma unroll
            for (int nt = 0; nt < 4; ++nt) {
                short8 bhi = *(const short8*)&Bs[0][nt * 16 + lm][ki * 32 + lg * 8];
                short8 blo = *(const short8*)&Bs[1][nt * 16 + lm][ki * 32 + lg * 8];
                acc[nt][0] = __builtin_amdgcn_mfma_f32_16x16x32_bf16(ahi, bhi, acc[nt][0], 0, 0, 0);
                acc[nt][1] = __builtin_amdgcn_mfma_f32_16x16x32_bf16(ahi, blo, acc[nt][1], 0, 0, 0);
                acc[nt][2] = __builtin_amdgcn_mfma_f32_16x16x32_bf16(alo, bhi, acc[nt][2], 0, 0, 0);
            }
        }
        __syncthreads();
    }
    const int m = t + 1;
#pragma unroll
    for (int nt = 0; nt < 4; ++nt) {
        f32x4 s4 = acc[nt][0] + acc[nt][1] + acc[nt][2];
        int r = r0 + nt * 16 + lm;
        float bias = b_in[r];
#pragma unroll
        for (int j = 0; j < 4; ++j) {
            int bb = w * 16 + lg * 4 + j;
            float v = s4[j] + bias;
            unsigned short h = f2bf(v);
            long o = ((long)m * B_ + bb) * DRES + r;
            st_hi[o] = h;
            st_lo[o] = f2bf(v - bf2f(h));
        }
    }
}

// ---------------- persistent recurrence: 8 clusters x 32 WGs ----------------
// 256 WGs x 512 threads. Cluster cl = bid>>5 owns batch [cl*8,+8).
// WG wgl = bid&31 owns W rows [wgl*64,+64): hi plane in LDS, lo in VGPRs.
// Wave ks = K window [ks*256,+256), gated on 4 producer WGs x 8 waves.
#define MFI8(a, b, c) __builtin_amdgcn_mfma_i32_16x16x64_i8(a, b, c, 0, 0, 0)
#define PRM(hi, lo, sel) \
    (int)__builtin_amdgcn_perm((unsigned)(hi), (unsigned)(lo), (sel))

__global__ __launch_bounds__(512) void recur_persist(
    const char* __restrict__ wq1, const char* __restrict__ wq0,
    unsigned short* __restrict__ hq,
    unsigned short* __restrict__ st_hi, const unsigned short* __restrict__ st_lo,
    unsigned* __restrict__ bar) {
    extern __shared__ char smem[];           // [0,128K): W-hi rows, [128K,160K): red dbuf
    float* redf = (float*)(smem + 131072);   // [2][8 ks][8 b][64 row] f32 (16KB each)
    const int bid = blockIdx.x;
    const int cl  = bid >> 5;                // cluster 0..7
    const int wgl = bid & 31;                // WG within cluster
    const int cb0 = cl * 8;
    const int tid = threadIdx.x;
    const int w = tid >> 6, l = tid & 63;
    const int lm = l & 15, lg = l >> 4;
    const int ks = w;                        // K window (8 x 256)
    const size_t SL = (size_t)B_ * DRES;
    unsigned* flags = bar + cl * 256;        // [32 wg][8 wave]

    // ---- stage W-hi plane (64 rows, swizzled 16B chunks) ----
    const size_t wbase = (size_t)wgl * 64 * 2048;
    for (int c = tid; c < 8192; c += 512) {
        int row = c >> 7, k16 = c & 127;
        const char* src = wq1 + wbase + (size_t)row * 2048 + k16 * 16;
        int dst = row * 2048 + ((k16 * 16) ^ ((row & 7) << 4));
        *(i32x4*)(smem + dst) = *(const i32x4*)src;
    }
    // ---- W-lo plane for this wave's K-window into registers ----
    i32x4 wl[4][4];
#pragma unroll
    for (int rt = 0; rt < 4; ++rt)
#pragma unroll
        for (int c = 0; c < 4; ++c)
            wl[rt][c] = *(const i32x4*)(wq0 + wbase + (size_t)(rt * 16 + lm) * 2048
                                        + ks * 256 + c * 64 + lg * 16);
    __syncthreads();

    const int swz = (lm & 7) << 4;
    const int lgo = lg * 16;
    const unsigned* gatef = flags + ks * 32 + (l & 31);   // 4 producer WGs x 8 waves
    unsigned* ownf = flags + wgl * 8 + w;

    // distributed-epilogue mapping: thread owns (batch cb0+w, row wgl*64+l)
    const int grow = wgl * 64 + l;
    const size_t eoff = (size_t)(cb0 + w) * DRES + grow;

    for (int m = 1; m < T_; ++m) {
        // u prefetch (plain cached; latency hides under gate/A-load)
        unsigned short uh = st_hi[(size_t)m * SL + eoff];
        unsigned short ul = st_lo[(size_t)m * SL + eoff];

        // per-wave gate: 4 producer WGs (rows [ks*256,+256)) x 8 waves done
        if (m > 1) {
            int it_ = 0;
            while (true) {
                unsigned pv;
                asm volatile("global_load_dword %0, %1, off sc0 sc1" : "=v"(pv) : "v"(gatef));
                asm volatile("s_waitcnt vmcnt(0)" ::: "memory");
                if (__all(pv >= (unsigned)(m - 1))) break;
                if (++it_ > (1 << 18)) break;
                __builtin_amdgcn_s_sleep(1);
            }
        }

        // A loads (packed i16): batch row lm&7, K window [ks*256,+256)
        const char* pA = (const char*)hq + (size_t)((m - 1) & 3) * SLQB
                       + (size_t)(cb0 + (lm & 7)) * 4096 + ks * 512 + lg * 32;
        i32x4 U[8];
#pragma unroll
        for (int c = 0; c < 4; ++c) {
            asm volatile("global_load_dwordx4 %0, %1, off sc0 sc1"
                         : "=v"(U[c * 2]) : "v"(pA + c * 128));
            asm volatile("global_load_dwordx4 %0, %1, off sc0 sc1"
                         : "=v"(U[c * 2 + 1]) : "v"(pA + c * 128 + 16));
        }
        asm volatile("s_waitcnt vmcnt(0)" ::: "memory");
        __builtin_amdgcn_sched_barrier(0);

        i32x4 A11[4], A10[4], A01[4], A00[4];
#pragma unroll
        for (int rt = 0; rt < 4; ++rt) {
            A11[rt] = (i32x4)0; A10[rt] = (i32x4)0; A01[rt] = (i32x4)0; A00[rt] = (i32x4)0;
        }
#pragma unroll
        for (int c = 0; c < 4; ++c) {
            i32x4 v0 = U[c * 2], v1 = U[c * 2 + 1];
            i32x4 ah0, ah1;
            ah0[0] = PRM(v0[1], v0[0], 0x06040200u); ah1[0] = PRM(v0[1], v0[0], 0x07050301u);
            ah0[1] = PRM(v0[3], v0[2], 0x06040200u); ah1[1] = PRM(v0[3], v0[2], 0x07050301u);
            ah0[2] = PRM(v1[1], v1[0], 0x06040200u); ah1[2] = PRM(v1[1], v1[0], 0x07050301u);
            ah0[3] = PRM(v1[3], v1[2], 0x06040200u); ah1[3] = PRM(v1[3], v1[2], 0x07050301u);
            int kbs = (ks * 256 + c * 64 + lgo) ^ swz;
#pragma unroll
            for (int rt = 0; rt < 4; ++rt) {
                i32x4 b1 = *(const i32x4*)(smem + (size_t)(rt * 16 + lm) * 2048 + kbs);
                i32x4 b0 = wl[rt][c];
                A11[rt] = MFI8(ah1, b1, A11[rt]);
                A10[rt] = MFI8(ah1, b0, A10[rt]);
                A01[rt] = MFI8(ah0, b1, A01[rt]);
                A00[rt] = MFI8(ah0, b0, A00[rt]);
            }
        }
        // combine digit products; publish partials into red[m&1][ks][b][row]
        float* rw = redf + (size_t)(m & 1) * 4096 + (size_t)ks * 512;
#pragma unroll
        for (int rt = 0; rt < 4; ++rt) {
            f32x4 pf;
#pragma unroll
            for (int j = 0; j < 4; ++j)
                pf[j] = 65536.f * (float)A11[rt][j]
                      + 256.f * (float)(A10[rt][j] + A01[rt][j])
                      + (float)A00[rt][j];
            if (lg < 2) {   // real batch 0..7 only (8..15 are duplicates)
#pragma unroll
                for (int j = 0; j < 4; ++j)
                    rw[(lg * 4 + j) * 64 + rt * 16 + lm] = pf[j];
            }
        }
        __syncthreads();   // the only barrier per step (red dbuf protects reuse)

        // distributed epilogue: thread owns (batch cb0+w, row grow)
        const float* rb = redf + (size_t)(m & 1) * 4096 + w * 64 + l;
        float s = 0.f;
#pragma unroll
        for (int p = 0; p < 8; ++p) s += rb[(size_t)p * 512];
        float pre = s * 0x1p-30f + bf2f(uh) + bf2f(ul);
        float ex = __expf(2.f * pre);
        float h = 1.f - 2.f * __builtin_amdgcn_rcpf(ex + 1.f);
        if (m < T_ - 1) {
            int q = (int)rintf(h * 16384.f);
            int d1 = (q + 128) >> 8;
            int d0 = q - (d1 << 8);
            unsigned pk = (unsigned)(d0 & 0xFF) | ((unsigned)(d1 & 0xFF) << 8);
            const unsigned short* dst = hq + (size_t)(m & 3) * SLP + eoff;
            asm volatile("global_store_short %0, %1, off sc0 sc1"
                         :: "v"(dst), "v"(pk) : "memory");
            // per-wave release: drain own stores, then publish this wave's flag
            asm volatile("s_waitcnt vmcnt(0)" ::: "memory");
            if (l == 0) {
                unsigned mv = (unsigned)m;
                asm volatile("global_store_dword %0, %1, off sc0 sc1"
                             :: "v"(ownf), "v"(mv) : "memory");
            }
        }
        st_hi[(size_t)m * SL + eoff] = f2bf(h);   // bf16 state for readout (cached)
    }
}

// ---------------- readout: out[b][t][o] = states[t][b][:] . W_out[o][:] + b_out ----------------
__global__ __launch_bounds__(256) void readout_kern(
    const unsigned short* __restrict__ st_hi,
    const unsigned short* __restrict__ Wout_hi,
    const float* __restrict__ b_out, float* __restrict__ out) {
    const int n0 = blockIdx.x * 128;
    const int row0 = blockIdx.y * 64;
    const int tid = threadIdx.x;
    const int w = tid >> 6, l = tid & 63;
    const int lm = l & 15, lg = l >> 4;

    __shared__ __align__(16) unsigned short Bs[128][72];

    f32x4 acc[8];
#pragma unroll
    for (int nt = 0; nt < 8; ++nt) acc[nt] = (f32x4)0.f;

    const int row = row0 + w * 16 + lm;
    const long abase = (long)row * DRES;

    for (int s = 0; s < 32; ++s) {
#pragma unroll
        for (int q = 0; q < 4; ++q) {
            int idx = q * 256 + tid;
            int r_ = idx >> 3, k8 = idx & 7;
            *(short8*)&Bs[r_][k8 * 8] =
                *(const short8*)(Wout_hi + (long)(n0 + r_) * DRES + s * 64 + k8 * 8);
        }
        __syncthreads();
#pragma unroll
        for (int ki = 0; ki < 2; ++ki) {
            short8 a = *(const short8*)&st_hi[abase + s * 64 + ki * 32 + lg * 8];
#pragma unroll
            for (int nt = 0; nt < 8; ++nt) {
                short8 bf = *(const short8*)&Bs[nt * 16 + lm][ki * 32 + lg * 8];
                acc[nt] = __builtin_amdgcn_mfma_f32_16x16x32_bf16(a, bf, acc[nt], 0, 0, 0);
            }
        }
        __syncthreads();
    }
#pragma unroll
    for (int nt = 0; nt < 8; ++nt) {
        int o = n0 + nt * 16 + lm;
        float bias = b_out[o];
#pragma unroll
        for (int j = 0; j < 4; ++j) {
            int rr = row0 + w * 16 + lg * 4 + j;
            int t = rr >> 6, bb = rr & 63;
            out[((long)bb * T_ + t) * DOUT + o] = acc[nt][j] + bias;
        }
    }
}

extern "C" void kernel_launch(void* const* d_in, const int* in_sizes, int n_in,
                              void* d_out, int out_size, void* d_ws, size_t ws_size,
                              hipStream_t stream) {
    const float* x_res_init = (const float*)d_in[0];
    const float* x_in       = (const float*)d_in[1];
    const float* W_in       = (const float*)d_in[2];
    const float* b_in       = (const float*)d_in[3];
    const float* W_res      = (const float*)d_in[4];
    const float* W_out      = (const float*)d_in[5];
    const float* b_out      = (const float*)d_in[6];
    float* out = (float*)d_out;

    char* p = (char*)d_ws;
    auto alloc = [&](size_t bytes) -> char* {
        char* r = p;
        p += (bytes + 255) & ~(size_t)255;
        return r;
    };
    const size_t SL = (size_t)B_ * DRES;
    unsigned short* st_hi   = (unsigned short*)alloc((size_t)T_ * SL * 2);
    unsigned short* st_lo   = (unsigned short*)alloc((size_t)T_ * SL * 2);
    char*           wq1     = alloc((size_t)DRES * DRES);
    char*           wq0     = alloc((size_t)DRES * DRES);
    unsigned short* hq      = (unsigned short*)alloc(4 * (size_t)SLQB);
    unsigned short* Win_hi  = (unsigned short*)alloc((size_t)DRES * DIN * 2);
    unsigned short* Win_lo  = (unsigned short*)alloc((size_t)DRES * DIN * 2);
    unsigned short* Wout_hi = (unsigned short*)alloc((size_t)DOUT * DRES * 2);
    unsigned short* Wout_lo = (unsigned short*)alloc((size_t)DOUT * DRES * 2);
    unsigned short* x_hi    = (unsigned short*)alloc((size_t)B_ * T_ * DIN * 2);
    unsigned short* x_lo    = (unsigned short*)alloc((size_t)B_ * T_ * DIN * 2);
    unsigned*       bar     = (unsigned*)alloc(8192);   // 8 clusters x 32 wg x 8 waves

    hipMemsetAsync(bar, 0, 8192, stream);   // flags are per-launch monotonic

    auto launch_split = [&](const float* src, unsigned short* hi, unsigned short* lo, size_t n) {
        int n4 = (int)(n / 4);
        int blocks = (n4 + 255) / 256;
        if (blocks > 2048) blocks = 2048;
        split4_kern<<<blocks, 256, 0, stream>>>((const float4*)src, (ushort4*)hi, (ushort4*)lo, n4);
    };
    launch_split(W_in,  Win_hi,  Win_lo,  (size_t)DRES * DIN);
    launch_split(W_out, Wout_hi, Wout_lo, (size_t)DOUT * DRES);
    launch_split(x_in,  x_hi,    x_lo,    (size_t)B_ * T_ * DIN);
    launch_split(x_res_init, st_hi, st_lo, SL);   // states[0] (bf16, for readout)

    // quantize W_res (two i8 planes, scale 2^16) and h_0 (packed i16, slot 0)
    quant_kern<<<2048, 256, 0, stream>>>(W_res, 65536.f, wq1, wq0, DRES * DRES);
    quantp_kern<<<512, 256, 0, stream>>>(x_res_init, 16384.f, hq, B_ * DRES);

    // u into states[1..255]
    u_gemm<<<dim3(32, T_ - 1), 256, 0, stream>>>(x_hi, x_lo, Win_hi, Win_lo, b_in, st_hi, st_lo);

    // persistent recurrence: 256 WGs x 512 threads (8 clusters x 32 WGs), 160 KiB LDS
    const size_t shmem = 131072 + 32768;   // W-hi plane + red dbuf = 163840
    hipFuncSetAttribute(reinterpret_cast<const void*>(recur_persist),
                        hipFuncAttributeMaxDynamicSharedMemorySize, (int)shmem);
    void* kargs[] = { (void*)&wq1, (void*)&wq0, (void*)&hq,
                      (void*)&st_hi, (void*)&st_lo, (void*)&bar };
    hipLaunchCooperativeKernel((const void*)recur_persist, dim3(256), dim3(512),
                               kargs, (unsigned int)shmem, stream);

    // readout
    readout_kern<<<dim3(4, 256), 256, 0, stream>>>(st_hi, Wout_hi, b_out, out);
}